// Round 1
// 206.754 us; speedup vs baseline: 1.2211x; 1.2211x over previous
//
#include <hip/hip_runtime.h>
#include <stdint.h>

typedef int  v4i  __attribute__((ext_vector_type(4)));
typedef int  v16i __attribute__((ext_vector_type(16)));
typedef unsigned int uint32;

#define BATCH 16384
#define FEAT  1024

// ---- workspace layout (bytes) ----
// Activations in MFMA B-fragment layout: frag16B index = (nb*32 + kk)*64 + lane
//   value(byte j) = act[row = kk*32 + (j&3) + 8*(j>>2) + 4*(lane>>5)][col = nb*32 + (lane&31)]
// Weights in matching A-fragment layout (same sigma permutation of K).
#define OFF_ACTA 0u            // 16 MB  (Xp / H2)
#define OFF_ACTB 16777216u     // 16 MB  (H1 / H3)
#define OFF_WA1  33554432u     // 1 MB
#define OFF_WA2  34603008u     // 1 MB
#define OFF_WA3  35651584u     // 1 MB
#define OFF_WA4  36700160u     // 32 KB (10 rows + 22 zero-pad rows)
#define OFF_TH   36732928u     // 3*1024 int2

// ---------------------------------------------------------------------------
// prep: binarize to +-1 int8 and emit MFMA fragment layouts.
// Roles: b<512: X (thr 0.5) -> ACTA | 512..607: W1..W3 | 608: W4 (pad) | 609: TH
__global__ void __launch_bounds__(256) prep_kernel(
    const float* __restrict__ x,
    const float* __restrict__ W1, const float* __restrict__ W2,
    const float* __restrict__ W3, const float* __restrict__ W4,
    const float* __restrict__ g1, const float* __restrict__ b1,
    const float* __restrict__ m1, const float* __restrict__ v1,
    const float* __restrict__ g2, const float* __restrict__ b2,
    const float* __restrict__ m2, const float* __restrict__ v2,
    const float* __restrict__ g3, const float* __restrict__ b3,
    const float* __restrict__ m3, const float* __restrict__ v3,
    char* __restrict__ actA, char* __restrict__ wa1, char* __restrict__ wa2,
    char* __restrict__ wa3, char* __restrict__ wa4, int2* __restrict__ TH)
{
    int b = blockIdx.x;
    if (b == 609) {                       // thresholds (verified math, unchanged)
        for (int gid = threadIdx.x; gid < 3072; gid += 256) {
            int l = gid >> 10, j = gid & 1023;
            const float *g, *bb, *m, *v;
            if (l == 0)      { g = g1; bb = b1; m = m1; v = v1; }
            else if (l == 1) { g = g2; bb = b2; m = m2; v = v2; }
            else             { g = g3; bb = b3; m = m3; v = v3; }
            double gd = (double)g[j], bd = (double)bb[j], md = (double)m[j], vd = (double)v[j];
            double s = gd / sqrt(vd + 1e-5);
            int ti, flip;
            if (s > 0.0)      { ti = (int)ceil(md - bd / s);  flip = 0; }
            else if (s < 0.0) { ti = (int)floor(md - bd / s); flip = 1; }
            else              { ti = (bd >= 0.0) ? -2000000 : 2000000; flip = 0; }
            TH[gid] = make_int2(ti, flip);
        }
        return;
    }

    const float* src; char* dst; float thr; int nrows; int dblk;
    if (b < 512)      { src = x  + (size_t)b * 32768;            dst = actA; dblk = b;      thr = 0.5f; nrows = 32; }
    else if (b < 544) { int mb = b - 512; src = W1 + (size_t)mb * 32768; dst = wa1; dblk = mb; thr = 0.0f; nrows = 32; }
    else if (b < 576) { int mb = b - 544; src = W2 + (size_t)mb * 32768; dst = wa2; dblk = mb; thr = 0.0f; nrows = 32; }
    else if (b < 608) { int mb = b - 576; src = W3 + (size_t)mb * 32768; dst = wa3; dblk = mb; thr = 0.0f; nrows = 32; }
    else              { src = W4; dst = wa4; dblk = 0; thr = 0.0f; nrows = 10; }

    // stage 32 rows x 1024 cols as +-1 bytes into LDS (pitch 1040 to break conflicts)
    __shared__ unsigned char T[32][1040];
#pragma unroll
    for (int u = 0; u < 8; ++u) {
        int unit = threadIdx.x + u * 256;      // 0..2047
        int row  = unit >> 6;                  // 0..31
        int c16  = (unit & 63) << 4;           // col base (16 floats)
        uint32 wb0 = 0, wb1 = 0, wb2 = 0, wb3 = 0;
        if (row < nrows) {
            const float* p = src + (size_t)row * 1024 + c16;
            float4 f0 = *(const float4*)(p + 0);
            float4 f1 = *(const float4*)(p + 4);
            float4 f2 = *(const float4*)(p + 8);
            float4 f3 = *(const float4*)(p + 12);
            wb0 = (f0.x>=thr?0x01u:0xFFu) | ((f0.y>=thr?0x01u:0xFFu)<<8) | ((f0.z>=thr?0x01u:0xFFu)<<16) | ((f0.w>=thr?0x01u:0xFFu)<<24);
            wb1 = (f1.x>=thr?0x01u:0xFFu) | ((f1.y>=thr?0x01u:0xFFu)<<8) | ((f1.z>=thr?0x01u:0xFFu)<<16) | ((f1.w>=thr?0x01u:0xFFu)<<24);
            wb2 = (f2.x>=thr?0x01u:0xFFu) | ((f2.y>=thr?0x01u:0xFFu)<<8) | ((f2.z>=thr?0x01u:0xFFu)<<16) | ((f2.w>=thr?0x01u:0xFFu)<<24);
            wb3 = (f3.x>=thr?0x01u:0xFFu) | ((f3.y>=thr?0x01u:0xFFu)<<8) | ((f3.z>=thr?0x01u:0xFFu)<<16) | ((f3.w>=thr?0x01u:0xFFu)<<24);
        }
        *(uint4*)&T[row][c16] = make_uint4(wb0, wb1, wb2, wb3);
    }
    __syncthreads();

    // gather sigma-permuted 16B fragments, write coalesced
    int lane = threadIdx.x & 63;
    int wv   = threadIdx.x >> 6;
    int row  = lane & 31;
    int hb   = (lane >> 5) * 4;                 // +4h byte offset of sigma
#pragma unroll
    for (int u = 0; u < 8; ++u) {
        int kk = wv * 8 + u;
        const unsigned char* tr = &T[row][kk * 32 + hb];
        uint32 w0 = *(const uint32*)(tr + 0);   // k = kk*32 + 0..3  (+4h)
        uint32 w1 = *(const uint32*)(tr + 8);   // k = kk*32 + 8..11 (+4h)
        uint32 w2 = *(const uint32*)(tr + 16);  // k = kk*32 + 16..19(+4h)
        uint32 w3 = *(const uint32*)(tr + 24);  // k = kk*32 + 24..27(+4h)
        *(uint4*)(dst + (((size_t)dblk * 32 + kk) * 64 + lane) * 16) = make_uint4(w0, w1, w2, w3);
    }
}

// ---------------------------------------------------------------------------
// Binary GEMM layer on matrix cores: H^T = sign-threshold( W (+-1 i8) @ Hprev^T ).
// Block: 256 thr / 4 waves; wave holds one 32-row W-block's A-frags for full K
// in regs (128 VGPR); B (activations) double-buffered in LDS, shared by 4 waves.
// Grid 512 = 64 n-splits x 8 m-blocks, XCD-grouped so same-B blocks share L2.
__global__ void __launch_bounds__(256, 2) gemm_i8_kernel(
    const v4i* __restrict__ Af, const v4i* __restrict__ Bin,
    const int2* __restrict__ th, v4i* __restrict__ Bout)
{
    __shared__ v4i Bs[2][2048];                // 2 x 32 KB
    const int tid  = threadIdx.x;
    const int lane = tid & 63;
    const int wv   = tid >> 6;
    int bid = blockIdx.x;
    int xcd = bid & 7;
    int i   = bid >> 3;
    int s   = xcd + ((i >> 3) << 3);           // n-split 0..63 (8 nb each)
    int m   = i & 7;                           // m-block (128 rows)
    int mt  = m * 4 + wv;                      // 32-row W tile 0..31
    int nb0 = s * 8;

    v4i r[8];
    {   // stage nb0 -> regs
        const v4i* srcp = Bin + (size_t)nb0 * 2048;
#pragma unroll
        for (int j = 0; j < 8; ++j) r[j] = srcp[j * 256 + tid];
    }
    // A-fragments, full K (32 x 16B = 128 VGPR)
    v4i a[32];
    {
        const v4i* Ap = Af + (size_t)mt * 2048;
#pragma unroll
        for (int kk = 0; kk < 32; ++kk) a[kk] = Ap[kk * 64 + lane];
    }
    // thresholds for this wave's 16 output rows (C-layout order)
    int tt[16], tf[16];
    {
        const int2* thp = th + mt * 32;
        int hi4 = (lane >> 5) * 4;
#pragma unroll
        for (int q = 0; q < 16; ++q) {
            int2 t = thp[(q & 3) + 8 * (q >> 2) + hi4];
            tt[q] = t.x; tf[q] = t.y;
        }
    }
#pragma unroll
    for (int j = 0; j < 8; ++j) Bs[0][j * 256 + tid] = r[j];
    __syncthreads();

    int buf = 0;
#pragma unroll 1
    for (int it = 0; it < 8; ++it) {
        if (it < 7) {                           // issue next-tile loads early
            const v4i* srcp = Bin + (size_t)(nb0 + it + 1) * 2048;
#pragma unroll
            for (int j = 0; j < 8; ++j) r[j] = srcp[j * 256 + tid];
        }
        v16i acc;
#pragma unroll
        for (int z = 0; z < 16; ++z) acc[z] = 0;
#pragma unroll
        for (int kk = 0; kk < 32; ++kk) {
            v4i bfrag = Bs[buf][kk * 64 + lane];
            acc = __builtin_amdgcn_mfma_i32_32x32x32_i8(a[kk], bfrag, acc, 0, 0, 0);
        }
        // threshold -> +-1 bytes; acc bytes land exactly in next layer's B-frag slots
        uint32 wds0 = 0, wds1 = 0, wds2 = 0, wds3 = 0;
#pragma unroll
        for (int bq = 0; bq < 4; ++bq) {
            { int q = bq;      int h = acc[q]; int bit = tf[q] ? (h <= tt[q]) : (h >= tt[q]); wds0 |= (bit ? 0x01u : 0xFFu) << (8 * bq); }
            { int q = 4 + bq;  int h = acc[q]; int bit = tf[q] ? (h <= tt[q]) : (h >= tt[q]); wds1 |= (bit ? 0x01u : 0xFFu) << (8 * bq); }
            { int q = 8 + bq;  int h = acc[q]; int bit = tf[q] ? (h <= tt[q]) : (h >= tt[q]); wds2 |= (bit ? 0x01u : 0xFFu) << (8 * bq); }
            { int q = 12 + bq; int h = acc[q]; int bit = tf[q] ? (h <= tt[q]) : (h >= tt[q]); wds3 |= (bit ? 0x01u : 0xFFu) << (8 * bq); }
        }
        v4i ov; ov[0] = (int)wds0; ov[1] = (int)wds1; ov[2] = (int)wds2; ov[3] = (int)wds3;
        Bout[((size_t)(nb0 + it) * 32 + mt) * 64 + lane] = ov;

        if (it < 7) {
#pragma unroll
            for (int j = 0; j < 8; ++j) Bs[buf ^ 1][j * 256 + tid] = r[j];
            __syncthreads();
            buf ^= 1;
        }
    }
}

// ---------------------------------------------------------------------------
// Final 1024 -> 10 via MFMA (W4 zero-padded to 32 rows) + TensorNorm.
__global__ void __launch_bounds__(256) final_kernel(
    const v4i* __restrict__ Af4, const v4i* __restrict__ B3,
    const float* __restrict__ tw, const float* __restrict__ tb,
    const float* __restrict__ tm, const float* __restrict__ tv,
    float* __restrict__ out)
{
    int lane = threadIdx.x & 63;
    int nb   = blockIdx.x * 4 + (threadIdx.x >> 6);
    const v4i* Bf = B3 + (size_t)nb * 2048;
    v16i acc;
#pragma unroll
    for (int z = 0; z < 16; ++z) acc[z] = 0;
#pragma unroll
    for (int kk = 0; kk < 32; ++kk) {
        v4i av = Af4[kk * 64 + lane];
        v4i bv = Bf[kk * 64 + lane];
        acc = __builtin_amdgcn_mfma_i32_32x32x32_i8(av, bv, acc, 0, 0, 0);
    }
    double sc  = (double)tw[0] / sqrt((double)tv[0] + 1e-4);
    double off = (double)tb[0] - (double)tm[0] * sc;
    int colg = nb * 32 + (lane & 31);
    int hi   = lane >> 5;
#pragma unroll
    for (int q = 0; q < 8; ++q) {
        int rr = (q & 3) + 8 * (q >> 2) + 4 * hi;
        if (rr < 10)
            out[(size_t)colg * 10 + rr] = (float)((double)acc[q] * sc + off);
    }
}

// ---------------------------------------------------------------------------
extern "C" void kernel_launch(void* const* d_in, const int* in_sizes, int n_in,
                              void* d_out, int out_size, void* d_ws, size_t ws_size,
                              hipStream_t stream) {
    const float* x  = (const float*)d_in[0];
    const float* W1 = (const float*)d_in[1];
    const float* W2 = (const float*)d_in[2];
    const float* W3 = (const float*)d_in[3];
    const float* W4 = (const float*)d_in[4];
    const float* g1 = (const float*)d_in[5];
    const float* b1 = (const float*)d_in[6];
    const float* m1 = (const float*)d_in[7];
    const float* v1 = (const float*)d_in[8];
    const float* g2 = (const float*)d_in[9];
    const float* b2 = (const float*)d_in[10];
    const float* m2 = (const float*)d_in[11];
    const float* v2 = (const float*)d_in[12];
    const float* g3 = (const float*)d_in[13];
    const float* b3 = (const float*)d_in[14];
    const float* m3 = (const float*)d_in[15];
    const float* v3 = (const float*)d_in[16];
    const float* tw = (const float*)d_in[17];
    const float* tb = (const float*)d_in[18];
    const float* tm = (const float*)d_in[19];
    const float* tv = (const float*)d_in[20];

    char* ws = (char*)d_ws;
    char* actA = ws + OFF_ACTA;
    char* actB = ws + OFF_ACTB;
    char* wa1  = ws + OFF_WA1;
    char* wa2  = ws + OFF_WA2;
    char* wa3  = ws + OFF_WA3;
    char* wa4  = ws + OFF_WA4;
    int2* TH   = (int2*)(ws + OFF_TH);

    prep_kernel<<<610, 256, 0, stream>>>(x, W1, W2, W3, W4,
                                         g1, b1, m1, v1, g2, b2, m2, v2,
                                         g3, b3, m3, v3,
                                         actA, wa1, wa2, wa3, wa4, TH);

    gemm_i8_kernel<<<512, 256, 0, stream>>>((const v4i*)wa1, (const v4i*)actA, TH,        (v4i*)actB);
    gemm_i8_kernel<<<512, 256, 0, stream>>>((const v4i*)wa2, (const v4i*)actB, TH + 1024, (v4i*)actA);
    gemm_i8_kernel<<<512, 256, 0, stream>>>((const v4i*)wa3, (const v4i*)actA, TH + 2048, (v4i*)actB);

    final_kernel<<<128, 256, 0, stream>>>((const v4i*)wa4, (const v4i*)actB,
                                          tw, tb, tm, tv, (float*)d_out);
}

// Round 2
// 200.143 us; speedup vs baseline: 1.2615x; 1.0330x over previous
//
#include <hip/hip_runtime.h>
#include <stdint.h>

typedef int  v4i  __attribute__((ext_vector_type(4)));
typedef int  v16i __attribute__((ext_vector_type(16)));
typedef unsigned int uint32;

#define BATCH 16384
#define FEAT  1024

// ---- workspace layout (bytes) ----
// Activations in MFMA B-fragment layout: frag16B index = (nb*32 + kk)*64 + lane
//   value(byte j) = act[row = kk*32 + (j&3) + 8*(j>>2) + 4*(lane>>5)][col = nb*32 + (lane&31)]
// Weights in matching A-fragment layout (same sigma permutation of K).
#define OFF_ACTA 0u            // 16 MB  (Xp / H2)
#define OFF_ACTB 16777216u     // 16 MB  (H1 / H3)
#define OFF_WA1  33554432u     // 1 MB
#define OFF_WA2  34603008u     // 1 MB
#define OFF_WA3  35651584u     // 1 MB
#define OFF_WA4  36700160u     // 32 KB (10 rows + 22 zero-pad rows)
#define OFF_TH   36732928u     // 3*1024 int2

// ---------------------------------------------------------------------------
// prep: binarize to +-1 int8 and emit MFMA fragment layouts. (verified R1)
__global__ void __launch_bounds__(256) prep_kernel(
    const float* __restrict__ x,
    const float* __restrict__ W1, const float* __restrict__ W2,
    const float* __restrict__ W3, const float* __restrict__ W4,
    const float* __restrict__ g1, const float* __restrict__ b1,
    const float* __restrict__ m1, const float* __restrict__ v1,
    const float* __restrict__ g2, const float* __restrict__ b2,
    const float* __restrict__ m2, const float* __restrict__ v2,
    const float* __restrict__ g3, const float* __restrict__ b3,
    const float* __restrict__ m3, const float* __restrict__ v3,
    char* __restrict__ actA, char* __restrict__ wa1, char* __restrict__ wa2,
    char* __restrict__ wa3, char* __restrict__ wa4, int2* __restrict__ TH)
{
    int b = blockIdx.x;
    if (b == 609) {                       // thresholds (verified math, unchanged)
        for (int gid = threadIdx.x; gid < 3072; gid += 256) {
            int l = gid >> 10, j = gid & 1023;
            const float *g, *bb, *m, *v;
            if (l == 0)      { g = g1; bb = b1; m = m1; v = v1; }
            else if (l == 1) { g = g2; bb = b2; m = m2; v = v2; }
            else             { g = g3; bb = b3; m = m3; v = v3; }
            double gd = (double)g[j], bd = (double)bb[j], md = (double)m[j], vd = (double)v[j];
            double s = gd / sqrt(vd + 1e-5);
            int ti, flip;
            if (s > 0.0)      { ti = (int)ceil(md - bd / s);  flip = 0; }
            else if (s < 0.0) { ti = (int)floor(md - bd / s); flip = 1; }
            else              { ti = (bd >= 0.0) ? -2000000 : 2000000; flip = 0; }
            TH[gid] = make_int2(ti, flip);
        }
        return;
    }

    const float* src; char* dst; float thr; int nrows; int dblk;
    if (b < 512)      { src = x  + (size_t)b * 32768;            dst = actA; dblk = b;      thr = 0.5f; nrows = 32; }
    else if (b < 544) { int mb = b - 512; src = W1 + (size_t)mb * 32768; dst = wa1; dblk = mb; thr = 0.0f; nrows = 32; }
    else if (b < 576) { int mb = b - 544; src = W2 + (size_t)mb * 32768; dst = wa2; dblk = mb; thr = 0.0f; nrows = 32; }
    else if (b < 608) { int mb = b - 576; src = W3 + (size_t)mb * 32768; dst = wa3; dblk = mb; thr = 0.0f; nrows = 32; }
    else              { src = W4; dst = wa4; dblk = 0; thr = 0.0f; nrows = 10; }

    __shared__ unsigned char T[32][1040];
#pragma unroll
    for (int u = 0; u < 8; ++u) {
        int unit = threadIdx.x + u * 256;      // 0..2047
        int row  = unit >> 6;                  // 0..31
        int c16  = (unit & 63) << 4;           // col base (16 floats)
        uint32 wb0 = 0, wb1 = 0, wb2 = 0, wb3 = 0;
        if (row < nrows) {
            const float* p = src + (size_t)row * 1024 + c16;
            float4 f0 = *(const float4*)(p + 0);
            float4 f1 = *(const float4*)(p + 4);
            float4 f2 = *(const float4*)(p + 8);
            float4 f3 = *(const float4*)(p + 12);
            wb0 = (f0.x>=thr?0x01u:0xFFu) | ((f0.y>=thr?0x01u:0xFFu)<<8) | ((f0.z>=thr?0x01u:0xFFu)<<16) | ((f0.w>=thr?0x01u:0xFFu)<<24);
            wb1 = (f1.x>=thr?0x01u:0xFFu) | ((f1.y>=thr?0x01u:0xFFu)<<8) | ((f1.z>=thr?0x01u:0xFFu)<<16) | ((f1.w>=thr?0x01u:0xFFu)<<24);
            wb2 = (f2.x>=thr?0x01u:0xFFu) | ((f2.y>=thr?0x01u:0xFFu)<<8) | ((f2.z>=thr?0x01u:0xFFu)<<16) | ((f2.w>=thr?0x01u:0xFFu)<<24);
            wb3 = (f3.x>=thr?0x01u:0xFFu) | ((f3.y>=thr?0x01u:0xFFu)<<8) | ((f3.z>=thr?0x01u:0xFFu)<<16) | ((f3.w>=thr?0x01u:0xFFu)<<24);
        }
        *(uint4*)&T[row][c16] = make_uint4(wb0, wb1, wb2, wb3);
    }
    __syncthreads();

    int lane = threadIdx.x & 63;
    int wv   = threadIdx.x >> 6;
    int row  = lane & 31;
    int hb   = (lane >> 5) * 4;                 // +4h byte offset of sigma
#pragma unroll
    for (int u = 0; u < 8; ++u) {
        int kk = wv * 8 + u;
        const unsigned char* tr = &T[row][kk * 32 + hb];
        uint32 w0 = *(const uint32*)(tr + 0);
        uint32 w1 = *(const uint32*)(tr + 8);
        uint32 w2 = *(const uint32*)(tr + 16);
        uint32 w3 = *(const uint32*)(tr + 24);
        *(uint4*)(dst + (((size_t)dblk * 32 + kk) * 64 + lane) * 16) = make_uint4(w0, w1, w2, w3);
    }
}

// ---------------------------------------------------------------------------
// Async stage of one 32 KB B-tile into LDS (linear copy, fragment layout
// already matches wave-uniform-base + lane*16 -> global_load_lds fits).
__device__ __forceinline__ void stage_tile(v4i (*Bs)[2048], int bufi,
                                           const v4i* __restrict__ Bin,
                                           int tile, int wv, int lane) {
#pragma unroll
    for (int j = 0; j < 8; ++j) {
        __builtin_amdgcn_global_load_lds(
            (const __attribute__((address_space(1))) void*)
                (Bin + (size_t)tile * 2048 + j * 256 + wv * 64 + lane),
            (__attribute__((address_space(3))) void*)
                (&Bs[bufi][j * 256 + wv * 64]),
            16, 0, 0);
    }
}

// ---------------------------------------------------------------------------
// Binary GEMM layer on matrix cores: H^T = sign-threshold( W (+-1 i8) @ Hprev^T ).
// R2: (a) split-K dual accumulators (break the 32-deep dependent MFMA chain),
//     (b) global_load_lds async staging + counted s_waitcnt vmcnt(1) before
//         the barrier (stage loads drained, output store left in flight) --
//         removes the reg-staging vmcnt(0)+ds_write serialization (m233 stall).
__global__ void __launch_bounds__(256, 2) gemm_i8_kernel(
    const v4i* __restrict__ Af, const v4i* __restrict__ Bin,
    const int2* __restrict__ th, v4i* __restrict__ Bout)
{
    __shared__ v4i Bs[2][2048];                // 2 x 32 KB
    const int tid  = threadIdx.x;
    const int lane = tid & 63;
    const int wv   = tid >> 6;
    int bid = blockIdx.x;
    int xcd = bid & 7;
    int i   = bid >> 3;
    int s   = xcd + ((i >> 3) << 3);           // n-split 0..63, XCD-grouped
    int m   = i & 7;                           // m-block (128 rows)
    int mt  = m * 4 + wv;                      // 32-row W tile 0..31
    int nb0 = s * 8;

    stage_tile(Bs, 0, Bin, nb0, wv, lane);     // tile 0 in flight

    // A-fragments, full K (32 x 16B = 128 VGPR)
    v4i a[32];
    {
        const v4i* Ap = Af + (size_t)mt * 2048;
#pragma unroll
        for (int kk = 0; kk < 32; ++kk) a[kk] = Ap[kk * 64 + lane];
    }
    // thresholds for this wave's 16 output rows (C-layout order)
    int tt[16], tf[16];
    {
        const int2* thp = th + mt * 32;
        int hi4 = (lane >> 5) * 4;
#pragma unroll
        for (int q = 0; q < 16; ++q) {
            int2 t = thp[(q & 3) + 8 * (q >> 2) + hi4];
            tt[q] = t.x; tf[q] = t.y;
        }
    }
    asm volatile("s_waitcnt vmcnt(0)" ::: "memory");
    __builtin_amdgcn_s_barrier();

    int buf = 0;
#pragma unroll 1
    for (int it = 0; it < 8; ++it) {
        if (it < 7) stage_tile(Bs, buf ^ 1, Bin, nb0 + it + 1, wv, lane);

        v16i acc0, acc1;
#pragma unroll
        for (int z = 0; z < 16; ++z) { acc0[z] = 0; acc1[z] = 0; }
#pragma unroll
        for (int kk = 0; kk < 16; ++kk) {
            v4i b0 = Bs[buf][kk * 64 + lane];
            v4i b1 = Bs[buf][(kk + 16) * 64 + lane];
            acc0 = __builtin_amdgcn_mfma_i32_32x32x32_i8(a[kk],      b0, acc0, 0, 0, 0);
            acc1 = __builtin_amdgcn_mfma_i32_32x32x32_i8(a[kk + 16], b1, acc1, 0, 0, 0);
        }

        uint32 wds0 = 0, wds1 = 0, wds2 = 0, wds3 = 0;
#pragma unroll
        for (int bq = 0; bq < 4; ++bq) {
            { int q = bq;      int h = acc0[q] + acc1[q]; int bit = tf[q] ? (h <= tt[q]) : (h >= tt[q]); wds0 |= (bit ? 0x01u : 0xFFu) << (8 * bq); }
            { int q = 4 + bq;  int h = acc0[q] + acc1[q]; int bit = tf[q] ? (h <= tt[q]) : (h >= tt[q]); wds1 |= (bit ? 0x01u : 0xFFu) << (8 * bq); }
            { int q = 8 + bq;  int h = acc0[q] + acc1[q]; int bit = tf[q] ? (h <= tt[q]) : (h >= tt[q]); wds2 |= (bit ? 0x01u : 0xFFu) << (8 * bq); }
            { int q = 12 + bq; int h = acc0[q] + acc1[q]; int bit = tf[q] ? (h <= tt[q]) : (h >= tt[q]); wds3 |= (bit ? 0x01u : 0xFFu) << (8 * bq); }
        }
        v4i ov; ov[0] = (int)wds0; ov[1] = (int)wds1; ov[2] = (int)wds2; ov[3] = (int)wds3;
        Bout[((size_t)(nb0 + it) * 32 + mt) * 64 + lane] = ov;

        if (it < 7) {
            // stage loads (8 per wave) must land; the output store may float.
            asm volatile("s_waitcnt vmcnt(1)" ::: "memory");
            __builtin_amdgcn_s_barrier();
            buf ^= 1;
        }
    }
}

// ---------------------------------------------------------------------------
// Final 1024 -> 10 via MFMA (W4 zero-padded to 32 rows) + TensorNorm. (verified R1)
__global__ void __launch_bounds__(256) final_kernel(
    const v4i* __restrict__ Af4, const v4i* __restrict__ B3,
    const float* __restrict__ tw, const float* __restrict__ tb,
    const float* __restrict__ tm, const float* __restrict__ tv,
    float* __restrict__ out)
{
    int lane = threadIdx.x & 63;
    int nb   = blockIdx.x * 4 + (threadIdx.x >> 6);
    const v4i* Bf = B3 + (size_t)nb * 2048;
    v16i acc;
#pragma unroll
    for (int z = 0; z < 16; ++z) acc[z] = 0;
#pragma unroll
    for (int kk = 0; kk < 32; ++kk) {
        v4i av = Af4[kk * 64 + lane];
        v4i bv = Bf[kk * 64 + lane];
        acc = __builtin_amdgcn_mfma_i32_32x32x32_i8(av, bv, acc, 0, 0, 0);
    }
    double sc  = (double)tw[0] / sqrt((double)tv[0] + 1e-4);
    double off = (double)tb[0] - (double)tm[0] * sc;
    int colg = nb * 32 + (lane & 31);
    int hi   = lane >> 5;
#pragma unroll
    for (int q = 0; q < 8; ++q) {
        int rr = (q & 3) + 8 * (q >> 2) + 4 * hi;
        if (rr < 10)
            out[(size_t)colg * 10 + rr] = (float)((double)acc[q] * sc + off);
    }
}

// ---------------------------------------------------------------------------
extern "C" void kernel_launch(void* const* d_in, const int* in_sizes, int n_in,
                              void* d_out, int out_size, void* d_ws, size_t ws_size,
                              hipStream_t stream) {
    const float* x  = (const float*)d_in[0];
    const float* W1 = (const float*)d_in[1];
    const float* W2 = (const float*)d_in[2];
    const float* W3 = (const float*)d_in[3];
    const float* W4 = (const float*)d_in[4];
    const float* g1 = (const float*)d_in[5];
    const float* b1 = (const float*)d_in[6];
    const float* m1 = (const float*)d_in[7];
    const float* v1 = (const float*)d_in[8];
    const float* g2 = (const float*)d_in[9];
    const float* b2 = (const float*)d_in[10];
    const float* m2 = (const float*)d_in[11];
    const float* v2 = (const float*)d_in[12];
    const float* g3 = (const float*)d_in[13];
    const float* b3 = (const float*)d_in[14];
    const float* m3 = (const float*)d_in[15];
    const float* v3 = (const float*)d_in[16];
    const float* tw = (const float*)d_in[17];
    const float* tb = (const float*)d_in[18];
    const float* tm = (const float*)d_in[19];
    const float* tv = (const float*)d_in[20];

    char* ws = (char*)d_ws;
    char* actA = ws + OFF_ACTA;
    char* actB = ws + OFF_ACTB;
    char* wa1  = ws + OFF_WA1;
    char* wa2  = ws + OFF_WA2;
    char* wa3  = ws + OFF_WA3;
    char* wa4  = ws + OFF_WA4;
    int2* TH   = (int2*)(ws + OFF_TH);

    prep_kernel<<<610, 256, 0, stream>>>(x, W1, W2, W3, W4,
                                         g1, b1, m1, v1, g2, b2, m2, v2,
                                         g3, b3, m3, v3,
                                         actA, wa1, wa2, wa3, wa4, TH);

    gemm_i8_kernel<<<512, 256, 0, stream>>>((const v4i*)wa1, (const v4i*)actA, TH,        (v4i*)actB);
    gemm_i8_kernel<<<512, 256, 0, stream>>>((const v4i*)wa2, (const v4i*)actB, TH + 1024, (v4i*)actA);
    gemm_i8_kernel<<<512, 256, 0, stream>>>((const v4i*)wa3, (const v4i*)actA, TH + 2048, (v4i*)actB);

    final_kernel<<<128, 256, 0, stream>>>((const v4i*)wa4, (const v4i*)actB,
                                          tw, tb, tm, tv, (float*)d_out);
}